// Round 9
// baseline (28.186 us; speedup 1.0000x reference)
//
#include <hip/hip_runtime.h>

#define BB 16384
#define AA 512
#define NBLK 2048            // 2048 blocks x 4 waves x 2 rows = 16384 rows
#define WAVES 4
#define ROWS_PER_WAVE 2
#define NGRP 32              // hierarchical completion: 32 groups x 64 blocks
#define GRPSZ (NBLK / NGRP)  // 64

// One annotation pair (2 preds, 1 label, 1 weight) -> masked elem-mean loss.
__device__ __forceinline__ float ann_pair(float pp0, float pp1, int lab, float ww,
                                          bool& anyv) {
    const float m0 = fmaxf(pp0, 0.0f);
    const float e0 = __logf(1.0f + __expf(-fabsf(pp0)));
    const float m1 = fmaxf(pp1, 0.0f);
    const float e1 = __logf(1.0f + __expf(-fabsf(pp1)));
    // t=1: 0.5*(softplus(p0) + w*softplus(-p1))
    // t=0: 0.5*(w*softplus(-p0) + softplus(p1))
    const float pa = (lab == 1)
        ? 0.5f * ((m0 + e0) + ww * ((m1 - pp1) + e1))
        : 0.5f * (ww * ((m0 - pp0) + e0) + (m1 + e1));
    const bool v = (lab != -1);
    anyv |= v;
    return v ? pa : 0.0f;
}

// Fused single kernel. Cross-block completion uses HIERARCHICAL fan-in:
// R4/R6 showed 2048 same-address RMWs serialize (~25ns each = +30..85us).
// Here: 32 cache-line-separated group counters (max 64 RMWs per address,
// arriving spread + parallel across lines) + one 32-wide super counter.
// All cross-block ops are RELAXED agent-scope (coherence point, no L2
// writeback/invalidate maintenance); store->ticket order enforced by
// s_waitcnt vmcnt(0) (correctness proven in R6, absmax 0).
extern "C" __global__ void __launch_bounds__(256, 8)
mtl_fused(const float* __restrict__ preds, const int* __restrict__ labels,
          const float* __restrict__ weights,
          unsigned int* __restrict__ counters,      // 32 group ctrs @ 64B stride + super @2048
          unsigned long long* __restrict__ part,    // [NBLK] packed (cnt<<32 | sum)
          float* __restrict__ out) {
    const int tid  = threadIdx.x;
    const int wv   = tid >> 6;
    const int lane = tid & 63;
    const int gw   = blockIdx.x * WAVES + wv;
    const int row0 = gw * ROWS_PER_WAVE;

    // weights for this lane's 8 annotations (4 per chunk), shared by both rows
    const float4* w4 = reinterpret_cast<const float4*>(weights);
    const float4 wA = w4[lane];        // ann 4*lane .. 4*lane+3
    const float4 wB = w4[lane + 64];   // ann 4*lane+256 ..

    float sum = 0.0f;
    float cnt = 0.0f;

    #pragma unroll
    for (int r = 0; r < ROWS_PER_WAVE; ++r) {
        const int row = row0 + r;
        const float4* pr = reinterpret_cast<const float4*>(preds + (size_t)row * (AA * 2));
        const int4*   lr = reinterpret_cast<const int4*>(labels + (size_t)row * AA);

        bool anyv = false;

        // chunk A: annotations 4*lane .. 4*lane+3
        {
            const float4 pa0 = pr[lane * 2];
            const float4 pa1 = pr[lane * 2 + 1];
            const int4   l   = lr[lane];
            sum += ann_pair(pa0.x, pa0.y, l.x, wA.x, anyv);
            sum += ann_pair(pa0.z, pa0.w, l.y, wA.y, anyv);
            sum += ann_pair(pa1.x, pa1.y, l.z, wA.z, anyv);
            sum += ann_pair(pa1.z, pa1.w, l.w, wA.w, anyv);
        }
        // chunk B: annotations 4*(lane+64) .. +3
        {
            const float4 pb0 = pr[(lane + 64) * 2];
            const float4 pb1 = pr[(lane + 64) * 2 + 1];
            const int4   l   = lr[lane + 64];
            sum += ann_pair(pb0.x, pb0.y, l.x, wB.x, anyv);
            sum += ann_pair(pb0.z, pb0.w, l.y, wB.y, anyv);
            sum += ann_pair(pb1.x, pb1.y, l.z, wB.z, anyv);
            sum += ann_pair(pb1.z, pb1.w, l.w, wB.w, anyv);
        }

        // all-invalid rows contribute 0 to sum; only has_valid needed
        cnt += (__ballot(anyv) != 0ULL) ? 1.0f : 0.0f;
    }

    #pragma unroll
    for (int off = 32; off > 0; off >>= 1) sum += __shfl_down(sum, off);
    // cnt is wave-uniform (ballot), no reduce needed

    __shared__ float2 sl[4];
    __shared__ bool   amLast;
    if (lane == 0) sl[wv] = make_float2(sum, cnt);
    __syncthreads();
    if (tid == 0) {
        const float2 a = sl[0], b = sl[1], c2 = sl[2], d = sl[3];
        const float S = a.x + b.x + c2.x + d.x;
        const float C = a.y + b.y + c2.y + d.y;
        const unsigned long long packed =
            ((unsigned long long)__float_as_uint(C) << 32) | __float_as_uint(S);
        __hip_atomic_store(&part[blockIdx.x], packed,
                           __ATOMIC_RELAXED, __HIP_MEMORY_SCOPE_AGENT);
        // partial must be at the coherence point before the ticket
        asm volatile("s_waitcnt vmcnt(0)" ::: "memory");
        bool last = false;
        const int grp = blockIdx.x >> 6;                 // /GRPSZ
        unsigned int* gctr = counters + grp * 16;        // 64 B stride
        const unsigned gp = __hip_atomic_fetch_add(gctr, 1u,
                             __ATOMIC_RELAXED, __HIP_MEMORY_SCOPE_AGENT);
        if (gp == GRPSZ - 1) {
            // group complete; its 64 partials are at the coherence point
            unsigned int* sctr = counters + NGRP * 16;
            const unsigned sp = __hip_atomic_fetch_add(sctr, 1u,
                                 __ATOMIC_RELAXED, __HIP_MEMORY_SCOPE_AGENT);
            last = (sp == NGRP - 1);
        }
        amLast = last;
    }
    __syncthreads();

    if (amLast) {
        float s = 0.0f, c = 0.0f;
        #pragma unroll
        for (int k = 0; k < NBLK / 256; ++k) {
            const unsigned long long v = __hip_atomic_load(&part[tid + (k << 8)],
                               __ATOMIC_RELAXED, __HIP_MEMORY_SCOPE_AGENT);
            s += __uint_as_float((unsigned)(v & 0xffffffffu));
            c += __uint_as_float((unsigned)(v >> 32));
        }
        #pragma unroll
        for (int off = 32; off > 0; off >>= 1) {
            s += __shfl_down(s, off);
            c += __shfl_down(c, off);
        }
        __shared__ float s2[4], c2a[4];
        if (lane == 0) { s2[wv] = s; c2a[wv] = c; }
        __syncthreads();
        if (tid == 0) {
            const float S = s2[0] + s2[1] + s2[2] + s2[3];
            const float C = c2a[0] + c2a[1] + c2a[2] + c2a[3];
            out[0] = S / fmaxf(C, 1.0f);
        }
    }
}

extern "C" void kernel_launch(void* const* d_in, const int* in_sizes, int n_in,
                              void* d_out, int out_size, void* d_ws, size_t ws_size,
                              hipStream_t stream) {
    const float* preds   = (const float*)d_in[0];
    const int*   labels  = (const int*)d_in[1];
    const float* weights = (const float*)d_in[2];
    float*       out     = (float*)d_out;

    unsigned int*       counters = (unsigned int*)d_ws;   // 32 grp @64B + super = 2052 B
    unsigned long long* part     = (unsigned long long*)((char*)d_ws + 4096);

    hipMemsetAsync(d_ws, 0, 4096, stream);                // zero all counters
    mtl_fused<<<NBLK, 256, 0, stream>>>(preds, labels, weights, counters, part, out);
}

// Round 10
// 25.869 us; speedup vs baseline: 1.0896x; 1.0896x over previous
//
#include <hip/hip_runtime.h>

#define BB 16384
#define AA 512
#define NBLK 1024            // 1024 blocks x 4 waves x 4 rows = 16384 rows
#define WAVES 4
#define ROWS_PER_WAVE 4

// One annotation pair (2 preds, 1 label, 1 weight) -> masked elem-mean loss.
__device__ __forceinline__ float ann_pair(float pp0, float pp1, int lab, float ww,
                                          bool& anyv) {
    const float m0 = fmaxf(pp0, 0.0f);
    const float e0 = __logf(1.0f + __expf(-fabsf(pp0)));
    const float m1 = fmaxf(pp1, 0.0f);
    const float e1 = __logf(1.0f + __expf(-fabsf(pp1)));
    // t=1: 0.5*(softplus(p0) + w*softplus(-p1))
    // t=0: 0.5*(w*softplus(-p0) + softplus(p1))
    const float pa = (lab == 1)
        ? ((m0 + e0) + ww * ((m1 - pp1) + e1))
        : (ww * ((m0 - pp0) + e0) + (m1 + e1));
    const bool v = (lab != -1);
    anyv |= v;
    return v ? pa : 0.0f;   // 0.5 factored out, applied once per wave
}

// One 64-lane wave per 4 consecutive rows. __launch_bounds__(256,4) allows
// 128 VGPRs so ALL 24 stream loads (4 rows x 6) are issued before compute:
// ~96 VGPRs of loads in flight per wave (vs ~5 loads under the 64-VGPR cap
// of (256,8)). Tests the "per-wave MLP is VGPR-capped" theory cleanly.
extern "C" __global__ void __launch_bounds__(256, 4)
mtl_partial(const float* __restrict__ preds, const int* __restrict__ labels,
            const float* __restrict__ weights, float2* __restrict__ part) {
    const int tid  = threadIdx.x;
    const int wv   = tid >> 6;
    const int lane = tid & 63;
    const int gw   = blockIdx.x * WAVES + wv;
    const int row0 = gw * ROWS_PER_WAVE;

    // weights for this lane's 8 annotations (4 per chunk), shared by all rows
    const float4* w4 = reinterpret_cast<const float4*>(weights);
    const float4 wA = w4[lane];        // ann 4*lane .. 4*lane+3
    const float4 wB = w4[lane + 64];   // ann 4*lane+256 ..

    // ---- issue ALL stream loads up front (24 x 16B per lane) ----
    float4 pa0[ROWS_PER_WAVE], pa1[ROWS_PER_WAVE];
    float4 pb0[ROWS_PER_WAVE], pb1[ROWS_PER_WAVE];
    int4   la[ROWS_PER_WAVE],  lb[ROWS_PER_WAVE];
    #pragma unroll
    for (int r = 0; r < ROWS_PER_WAVE; ++r) {
        const int row = row0 + r;
        const float4* pr = reinterpret_cast<const float4*>(preds + (size_t)row * (AA * 2));
        const int4*   lr = reinterpret_cast<const int4*>(labels + (size_t)row * AA);
        pa0[r] = pr[lane * 2];
        pa1[r] = pr[lane * 2 + 1];
        pb0[r] = pr[(lane + 64) * 2];
        pb1[r] = pr[(lane + 64) * 2 + 1];
        la[r]  = lr[lane];
        lb[r]  = lr[lane + 64];
    }

    // ---- compute ----
    float sum = 0.0f;
    float cnt = 0.0f;
    #pragma unroll
    for (int r = 0; r < ROWS_PER_WAVE; ++r) {
        bool anyv = false;
        sum += ann_pair(pa0[r].x, pa0[r].y, la[r].x, wA.x, anyv);
        sum += ann_pair(pa0[r].z, pa0[r].w, la[r].y, wA.y, anyv);
        sum += ann_pair(pa1[r].x, pa1[r].y, la[r].z, wA.z, anyv);
        sum += ann_pair(pa1[r].z, pa1[r].w, la[r].w, wA.w, anyv);
        sum += ann_pair(pb0[r].x, pb0[r].y, lb[r].x, wB.x, anyv);
        sum += ann_pair(pb0[r].z, pb0[r].w, lb[r].y, wB.y, anyv);
        sum += ann_pair(pb1[r].x, pb1[r].y, lb[r].z, wB.z, anyv);
        sum += ann_pair(pb1[r].z, pb1[r].w, lb[r].w, wB.w, anyv);
        // all-invalid rows contribute 0 to sum; only has_valid needed
        cnt += (__ballot(anyv) != 0ULL) ? 1.0f : 0.0f;
    }
    sum *= 0.5f;   // the factored-out elem-mean 1/2

    #pragma unroll
    for (int off = 32; off > 0; off >>= 1) sum += __shfl_down(sum, off);
    // cnt is wave-uniform (ballot), no reduce needed

    __shared__ float2 sl[4];
    if (lane == 0) sl[wv] = make_float2(sum, cnt);
    __syncthreads();
    if (tid == 0) {
        const float2 a = sl[0], b = sl[1], c = sl[2], d = sl[3];
        part[blockIdx.x] = make_float2(a.x + b.x + c.x + d.x,
                                       a.y + b.y + c.y + d.y);
    }
}

// Single-wave final reduction over 1024 float2 (8 KiB).
extern "C" __global__ void __launch_bounds__(64)
mtl_final(const float2* __restrict__ part, float* __restrict__ out) {
    const int lane = threadIdx.x;
    const float4* p4 = reinterpret_cast<const float4*>(part);  // 512 float4
    float s = 0.0f, c = 0.0f;
    #pragma unroll
    for (int k = 0; k < 8; ++k) {
        const float4 v = p4[lane + (k << 6)];
        s += v.x + v.z;
        c += v.y + v.w;
    }
    #pragma unroll
    for (int off = 32; off > 0; off >>= 1) {
        s += __shfl_down(s, off);
        c += __shfl_down(c, off);
    }
    if (lane == 0) out[0] = s / fmaxf(c, 1.0f);
}

extern "C" void kernel_launch(void* const* d_in, const int* in_sizes, int n_in,
                              void* d_out, int out_size, void* d_ws, size_t ws_size,
                              hipStream_t stream) {
    const float* preds   = (const float*)d_in[0];
    const int*   labels  = (const int*)d_in[1];
    const float* weights = (const float*)d_in[2];
    float*       out     = (float*)d_out;

    float2* part = (float2*)d_ws;   // 1024 * 8 B = 8 KiB

    mtl_partial<<<NBLK, 256, 0, stream>>>(preds, labels, weights, part);
    mtl_final<<<1, 64, 0, stream>>>(part, out);
}

// Round 11
// 23.535 us; speedup vs baseline: 1.1976x; 1.0992x over previous
//
#include <hip/hip_runtime.h>

#define BB 16384
#define AA 512
#define NBLK 2048            // 2048 blocks x 4 waves x 2 rows = 16384 rows
#define WAVES 4
#define ROWS_PER_WAVE 2
#define NPART (NBLK * WAVES) // 8192 per-wave partials

// One annotation pair (2 preds, 1 label, 1 weight) -> masked loss (x2;
// the elem-mean 0.5 is factored out and applied once per wave).
__device__ __forceinline__ float ann_pair(float pp0, float pp1, int lab, float ww,
                                          bool& anyv) {
    const float m0 = fmaxf(pp0, 0.0f);
    const float e0 = __logf(1.0f + __expf(-fabsf(pp0)));
    const float m1 = fmaxf(pp1, 0.0f);
    const float e1 = __logf(1.0f + __expf(-fabsf(pp1)));
    // t=1: softplus(p0) + w*softplus(-p1)
    // t=0: w*softplus(-p0) + softplus(p1)
    const float pa = (lab == 1)
        ? ((m0 + e0) + ww * ((m1 - pp1) + e1))
        : (ww * ((m0 - pp0) + e0) + (m1 + e1));
    const bool v = (lab != -1);
    anyv |= v;
    return v ? pa : 0.0f;
}

// R5 structure (best: 23.2us) with the block-level LDS reduction removed:
// each wave writes its own partial. No __syncthreads in the hot kernel.
extern "C" __global__ void __launch_bounds__(256, 8)
mtl_partial(const float* __restrict__ preds, const int* __restrict__ labels,
            const float* __restrict__ weights, float2* __restrict__ part) {
    const int tid  = threadIdx.x;
    const int wv   = tid >> 6;
    const int lane = tid & 63;
    const int gw   = blockIdx.x * WAVES + wv;
    const int row0 = gw * ROWS_PER_WAVE;

    // weights for this lane's 8 annotations (4 per chunk), shared by both rows
    const float4* w4 = reinterpret_cast<const float4*>(weights);
    const float4 wA = w4[lane];        // ann 4*lane .. 4*lane+3
    const float4 wB = w4[lane + 64];   // ann 4*lane+256 ..

    float sum = 0.0f;
    float cnt = 0.0f;

    #pragma unroll
    for (int r = 0; r < ROWS_PER_WAVE; ++r) {
        const int row = row0 + r;
        const float4* pr = reinterpret_cast<const float4*>(preds + (size_t)row * (AA * 2));
        const int4*   lr = reinterpret_cast<const int4*>(labels + (size_t)row * AA);

        bool anyv = false;

        // chunk A: annotations 4*lane .. 4*lane+3
        {
            const float4 pa0 = pr[lane * 2];
            const float4 pa1 = pr[lane * 2 + 1];
            const int4   l   = lr[lane];
            sum += ann_pair(pa0.x, pa0.y, l.x, wA.x, anyv);
            sum += ann_pair(pa0.z, pa0.w, l.y, wA.y, anyv);
            sum += ann_pair(pa1.x, pa1.y, l.z, wA.z, anyv);
            sum += ann_pair(pa1.z, pa1.w, l.w, wA.w, anyv);
        }
        // chunk B: annotations 4*(lane+64) .. +3
        {
            const float4 pb0 = pr[(lane + 64) * 2];
            const float4 pb1 = pr[(lane + 64) * 2 + 1];
            const int4   l   = lr[lane + 64];
            sum += ann_pair(pb0.x, pb0.y, l.x, wB.x, anyv);
            sum += ann_pair(pb0.z, pb0.w, l.y, wB.y, anyv);
            sum += ann_pair(pb1.x, pb1.y, l.z, wB.z, anyv);
            sum += ann_pair(pb1.z, pb1.w, l.w, wB.w, anyv);
        }

        // all-invalid rows contribute 0 to sum; only has_valid needed
        cnt += (__ballot(anyv) != 0ULL) ? 1.0f : 0.0f;
    }
    sum *= 0.5f;   // factored-out elem-mean 1/2

    #pragma unroll
    for (int off = 32; off > 0; off >>= 1) sum += __shfl_down(sum, off);
    // cnt is wave-uniform (ballot), no reduce needed

    if (lane == 0) part[gw] = make_float2(sum, cnt);
}

// Final reduction over 8192 float2 (64 KiB) with one 256-thread block.
extern "C" __global__ void __launch_bounds__(256)
mtl_final(const float2* __restrict__ part, float* __restrict__ out) {
    const int tid  = threadIdx.x;
    const int wv   = tid >> 6;
    const int lane = tid & 63;
    const float4* p4 = reinterpret_cast<const float4*>(part);  // 4096 float4
    float s = 0.0f, c = 0.0f;
    #pragma unroll
    for (int k = 0; k < 16; ++k) {
        const float4 v = p4[tid + (k << 8)];
        s += v.x + v.z;
        c += v.y + v.w;
    }
    #pragma unroll
    for (int off = 32; off > 0; off >>= 1) {
        s += __shfl_down(s, off);
        c += __shfl_down(c, off);
    }
    __shared__ float sl[4], cl[4];
    if (lane == 0) { sl[wv] = s; cl[wv] = c; }
    __syncthreads();
    if (tid == 0) {
        const float S = sl[0] + sl[1] + sl[2] + sl[3];
        const float C = cl[0] + cl[1] + cl[2] + cl[3];
        out[0] = S / fmaxf(C, 1.0f);
    }
}

extern "C" void kernel_launch(void* const* d_in, const int* in_sizes, int n_in,
                              void* d_out, int out_size, void* d_ws, size_t ws_size,
                              hipStream_t stream) {
    const float* preds   = (const float*)d_in[0];
    const int*   labels  = (const int*)d_in[1];
    const float* weights = (const float*)d_in[2];
    float*       out     = (float*)d_out;

    float2* part = (float2*)d_ws;   // 8192 * 8 B = 64 KiB

    mtl_partial<<<NBLK, 256, 0, stream>>>(preds, labels, weights, part);
    mtl_final<<<1, 256, 0, stream>>>(part, out);
}